// Round 1
// baseline (1563.165 us; speedup 1.0000x reference)
//
#include <hip/hip_runtime.h>
#include <cstddef>

#define NQ 2048   // batch B
#define NS 20000  // stars N
#define DD 64     // feature dim
#define DY 32     // label dim
#define LL 100    // unique labels

// ---------------- K0: norms, exp(-eta*ld) tables, matchIdx init ----------------
__global__ __launch_bounds__(256) void k_init(
    const float* __restrict__ star, const float* __restrict__ f1,
    const float* __restrict__ f2, const float* __restrict__ x,
    const float* __restrict__ ld1, const float* __restrict__ ld2,
    float* __restrict__ ns, float* __restrict__ nf1, float* __restrict__ nf2,
    float* __restrict__ nx, float* __restrict__ e1, float* __restrict__ e2,
    int* __restrict__ matchIdx)
{
  int t = blockIdx.x * 256 + threadIdx.x;
  if (t < NS) {
    const float4* a = (const float4*)(star + (size_t)t * DD);
    const float4* b = (const float4*)(f1 + (size_t)t * DD);
    const float4* c = (const float4*)(f2 + (size_t)t * DD);
    float sa = 0.f, sb = 0.f, sc = 0.f;
#pragma unroll
    for (int j = 0; j < 16; j++) {
      float4 va = a[j]; sa += va.x*va.x + va.y*va.y + va.z*va.z + va.w*va.w;
      float4 vb = b[j]; sb += vb.x*vb.x + vb.y*vb.y + vb.z*vb.z + vb.w*vb.w;
      float4 vc = c[j]; sc += vc.x*vc.x + vc.y*vc.y + vc.z*vc.z + vc.w*vc.w;
    }
    ns[t] = sa; nf1[t] = sb; nf2[t] = sc;
  } else if (t < NS + NQ) {
    int q = t - NS;
    const float4* a = (const float4*)(x + (size_t)q * DD);
    float s = 0.f;
#pragma unroll
    for (int j = 0; j < 16; j++) { float4 v = a[j]; s += v.x*v.x + v.y*v.y + v.z*v.z + v.w*v.w; }
    nx[q] = s;
    matchIdx[q] = NS;  // sentinel: no exact match
  } else if (t < NS + NQ + LL * LL) {
    int i = t - NS - NQ;
    e1[i] = __expf(-0.01f * ld1[i]);
    e2[i] = __expf(-0.01f * ld2[i]);
  }
}

// ---------------- K1: fused e_star pass ----------------
// block = 64 cols x 4 dim-groups. Per pair: dot(64) + acc f1,f2 (128 FMA) + sum.
// exp(2*dot - ns_i): the exp(-nx_b) factor cancels in the xt ratio.
__global__ __launch_bounds__(256) void k_star(
    const float* __restrict__ x, const float* __restrict__ star,
    const float* __restrict__ f1, const float* __restrict__ f2,
    const float* __restrict__ ns, const float* __restrict__ nx,
    float* __restrict__ pxt1, float* __restrict__ pxt2, float* __restrict__ psum,
    int* __restrict__ matchIdx, int chunk)
{
  __shared__ float pdl[8][4][64];
  const int tid = threadIdx.x;
  const int c = tid & 63;
  const int dg = __builtin_amdgcn_readfirstlane(tid >> 6);  // wave-uniform -> scalar addressing
  const int b = blockIdx.x * 64 + c;
  const int k = blockIdx.y;
  const int r0 = k * chunk;
  const int r1 = min(r0 + chunk, NS);  // always a multiple of 8 rows (NS%8==0, chunk%8==0)

  float xr[16];
  {
    const float4* xp = (const float4*)(x + (size_t)b * DD + dg * 16);
#pragma unroll
    for (int q = 0; q < 4; q++) {
      float4 v = xp[q];
      xr[4*q+0] = v.x; xr[4*q+1] = v.y; xr[4*q+2] = v.z; xr[4*q+3] = v.w;
    }
  }
  const float nxb = nx[b];
  float acc1[16], acc2[16];
#pragma unroll
  for (int j = 0; j < 16; j++) { acc1[j] = 0.f; acc2[j] = 0.f; }
  float esum = 0.f;
  int lmin = NS;

  for (int r = r0; r < r1; r += 8) {
    // partial dots over this thread's 16 dims, 8 rows
#pragma unroll
    for (int rr = 0; rr < 8; rr++) {
      const float4* sp = (const float4*)(star + (size_t)(r + rr) * DD + dg * 16);
      float pd = 0.f;
#pragma unroll
      for (int q = 0; q < 4; q++) {
        float4 v = sp[q];
        pd += v.x * xr[4*q+0] + v.y * xr[4*q+1] + v.z * xr[4*q+2] + v.w * xr[4*q+3];
      }
      pdl[rr][dg][c] = pd;
    }
    __syncthreads();
    float ev[8];
#pragma unroll
    for (int rr = 0; rr < 8; rr++) {
      float dot = pdl[rr][0][c] + pdl[rr][1][c] + pdl[rr][2][c] + pdl[rr][3][c];
      float nsr = ns[r + rr];
      if (nsr + nxb - 2.f * dot <= 0.f) lmin = min(lmin, r + rr);  // exact-match (never in practice)
      float e = __expf(2.f * dot - nsr);
      ev[rr] = e;
      esum += e;
    }
#pragma unroll
    for (int rr = 0; rr < 8; rr++) {
      const float4* ap = (const float4*)(f1 + (size_t)(r + rr) * DD + dg * 16);
      const float4* bp = (const float4*)(f2 + (size_t)(r + rr) * DD + dg * 16);
      const float e = ev[rr];
#pragma unroll
      for (int q = 0; q < 4; q++) {
        float4 va = ap[q];
        acc1[4*q+0] += e * va.x; acc1[4*q+1] += e * va.y;
        acc1[4*q+2] += e * va.z; acc1[4*q+3] += e * va.w;
      }
#pragma unroll
      for (int q = 0; q < 4; q++) {
        float4 vb = bp[q];
        acc2[4*q+0] += e * vb.x; acc2[4*q+1] += e * vb.y;
        acc2[4*q+2] += e * vb.z; acc2[4*q+3] += e * vb.w;
      }
    }
    __syncthreads();
  }

  float* o1 = pxt1 + ((size_t)k * NQ + b) * DD + dg * 16;
  float* o2 = pxt2 + ((size_t)k * NQ + b) * DD + dg * 16;
#pragma unroll
  for (int q = 0; q < 4; q++) {
    ((float4*)o1)[q] = make_float4(acc1[4*q], acc1[4*q+1], acc1[4*q+2], acc1[4*q+3]);
    ((float4*)o2)[q] = make_float4(acc2[4*q], acc2[4*q+1], acc2[4*q+2], acc2[4*q+3]);
  }
  if (dg == 0) psum[(size_t)k * NQ + b] = esum;
  if (lmin < NS) atomicMin(matchIdx + b, lmin);
}

// ---------------- K2: reduce partials -> xt, y = xt@W+b, y_idx = argmin dist ----------------
// one wave per query b
__global__ __launch_bounds__(256) void k_mid(
    const float* __restrict__ pxt1, const float* __restrict__ pxt2,
    const float* __restrict__ psum, const int* __restrict__ matchIdx,
    const float* __restrict__ f1, const float* __restrict__ f2,
    const float* __restrict__ W1, const float* __restrict__ b1,
    const float* __restrict__ W2, const float* __restrict__ b2,
    const float* __restrict__ u1, const float* __restrict__ u2,
    float* __restrict__ xt1, float* __restrict__ xt2,
    int* __restrict__ yid1, int* __restrict__ yid2, int nc1)
{
  __shared__ float xts[2][4][64];
  __shared__ float ys[4][64];
  const int lane = threadIdx.x & 63;
  const int w = __builtin_amdgcn_readfirstlane(threadIdx.x >> 6);
  const int b = blockIdx.x * 4 + w;

  float s1 = 0.f, s2 = 0.f, S = 0.f;
  for (int k = 0; k < nc1; k++) {
    s1 += pxt1[((size_t)k * NQ + b) * DD + lane];
    s2 += pxt2[((size_t)k * NQ + b) * DD + lane];
    S  += psum[(size_t)k * NQ + b];
  }
  const int m = matchIdx[b];
  float xa, xb;
  if (m < NS) {  // exact match: xt = feats[match_idx]
    xa = f1[(size_t)m * DD + lane];
    xb = f2[(size_t)m * DD + lane];
  } else {
    xa = s1 / S;
    xb = s2 / S;
  }
  xt1[(size_t)b * DD + lane] = xa;
  xt2[(size_t)b * DD + lane] = xb;
  xts[0][w][lane] = xa;
  xts[1][w][lane] = xb;
  __syncthreads();

  // y: lanes 0..31 -> branch1 dim j, lanes 32..63 -> branch2 dim j
  const int half = lane >> 5;
  const int j = lane & 31;
  const float* W = half ? W2 : W1;
  float y = (half ? b2 : b1)[j];
  for (int d = 0; d < DD; d++) y += xts[half][w][d] * W[d * DY + j];
  ys[w][lane] = y;
  __syncthreads();

#pragma unroll
  for (int p = 0; p < 2; p++) {
    const float* u = p ? u2 : u1;
    unsigned long long best = ~0ull;  // pack (dist_bits << 32) | idx: min => first argmin
#pragma unroll
    for (int h = 0; h < 2; h++) {
      int l = lane + h * 64;
      if (l < LL) {
        float dist = 0.f;
        for (int jj = 0; jj < DY; jj++) {
          float diff = ys[w][p * 32 + jj] - u[(size_t)l * DY + jj];
          dist += diff * diff;
        }
        unsigned long long pk = ((unsigned long long)__float_as_uint(dist) << 32) | (unsigned)l;
        best = best < pk ? best : pk;
      }
    }
#pragma unroll
    for (int off = 32; off > 0; off >>= 1) {
      unsigned long long o = __shfl_xor(best, off, 64);
      best = best < o ? best : o;
    }
    if (lane == 0) (p ? yid2 : yid1)[b] = (int)(best & 0xffffffffull);
  }
}

// ---------------- K3: fused e2 pass (one branch per launch) ----------------
// exp(2*f.xt - nf) * exp(-eta*ld): the exp(-|xt|^2) factor cancels in the ratio.
__global__ __launch_bounds__(256) void k_out(
    const float* __restrict__ xt, const float* __restrict__ f,
    const float* __restrict__ sl, const float* __restrict__ nf,
    const int* __restrict__ lidx, const int* __restrict__ yid,
    const float* __restrict__ eld_g,
    float* __restrict__ q, float* __restrict__ qs, int chunk)
{
  __shared__ float eld[LL * LL];     // 40 KB exp(-eta*ld) table
  __shared__ float pdl[8][4][64];
  const int tid = threadIdx.x;
  for (int i = tid * 4; i < LL * LL; i += 1024)
    *(float4*)(eld + i) = *(const float4*)(eld_g + i);

  const int c = tid & 63;
  const int dg = __builtin_amdgcn_readfirstlane(tid >> 6);
  const int b = blockIdx.x * 64 + c;
  const int k = blockIdx.y;
  const int r0 = k * chunk;
  const int r1 = min(r0 + chunk, NS);

  float xr[16];
  {
    const float4* xp = (const float4*)(xt + (size_t)b * DD + dg * 16);
#pragma unroll
    for (int qq = 0; qq < 4; qq++) {
      float4 v = xp[qq];
      xr[4*qq+0] = v.x; xr[4*qq+1] = v.y; xr[4*qq+2] = v.z; xr[4*qq+3] = v.w;
    }
  }
  const int yc = yid[b];
  float acc[8];
#pragma unroll
  for (int j = 0; j < 8; j++) acc[j] = 0.f;
  float es = 0.f;
  __syncthreads();

  for (int r = r0; r < r1; r += 8) {
#pragma unroll
    for (int rr = 0; rr < 8; rr++) {
      const float4* fp = (const float4*)(f + (size_t)(r + rr) * DD + dg * 16);
      float pd = 0.f;
#pragma unroll
      for (int qq = 0; qq < 4; qq++) {
        float4 v = fp[qq];
        pd += v.x * xr[4*qq+0] + v.y * xr[4*qq+1] + v.z * xr[4*qq+2] + v.w * xr[4*qq+3];
      }
      pdl[rr][dg][c] = pd;
    }
    __syncthreads();
    float ev[8];
#pragma unroll
    for (int rr = 0; rr < 8; rr++) {
      float dot = pdl[rr][0][c] + pdl[rr][1][c] + pdl[rr][2][c] + pdl[rr][3][c];
      float e = __expf(2.f * dot - nf[r + rr]) * eld[lidx[r + rr] * LL + yc];
      ev[rr] = e;
      es += e;
    }
#pragma unroll
    for (int rr = 0; rr < 8; rr++) {
      const float2* sp = (const float2*)(sl + (size_t)(r + rr) * DY + dg * 8);
      const float e = ev[rr];
#pragma unroll
      for (int qq = 0; qq < 4; qq++) {
        float2 v = sp[qq];
        acc[2*qq+0] += e * v.x;
        acc[2*qq+1] += e * v.y;
      }
    }
    __syncthreads();
  }
  float* o = q + ((size_t)k * NQ + b) * DY + dg * 8;
#pragma unroll
  for (int qq = 0; qq < 2; qq++)
    ((float4*)o)[qq] = make_float4(acc[4*qq], acc[4*qq+1], acc[4*qq+2], acc[4*qq+3]);
  if (dg == 0) qs[(size_t)k * NQ + b] = es;
}

// ---------------- K4: final reduce + average of branches ----------------
__global__ __launch_bounds__(256) void k_fin(
    const float* __restrict__ q1, const float* __restrict__ qs1,
    const float* __restrict__ q2, const float* __restrict__ qs2,
    float* __restrict__ out, int nc2)
{
  int t = blockIdx.x * 256 + threadIdx.x;
  if (t >= NQ * DY) return;
  int b = t >> 5, j = t & 31;
  float n1 = 0.f, d1 = 0.f, n2 = 0.f, d2 = 0.f;
  for (int k = 0; k < nc2; k++) {
    n1 += q1[((size_t)k * NQ + b) * DY + j];
    n2 += q2[((size_t)k * NQ + b) * DY + j];
    d1 += qs1[(size_t)k * NQ + b];
    d2 += qs2[(size_t)k * NQ + b];
  }
  out[t] = 0.5f * (n1 / d1 + n2 / d2);
}

extern "C" void kernel_launch(void* const* d_in, const int* in_sizes, int n_in,
                              void* d_out, int out_size, void* d_ws, size_t ws_size,
                              hipStream_t stream)
{
  const float* x    = (const float*)d_in[0];
  const float* star = (const float*)d_in[1];
  const float* slab = (const float*)d_in[2];
  const float* f1   = (const float*)d_in[3];
  const float* f2   = (const float*)d_in[4];
  const float* u1   = (const float*)d_in[5];
  const float* u2   = (const float*)d_in[6];
  const float* ld1  = (const float*)d_in[7];
  const float* ld2  = (const float*)d_in[8];
  const float* W1   = (const float*)d_in[9];
  const float* b1   = (const float*)d_in[10];
  const float* W2   = (const float*)d_in[11];
  const float* b2   = (const float*)d_in[12];
  const int* lidx1  = (const int*)d_in[13];
  const int* lidx2  = (const int*)d_in[14];
  float* out = (float*)d_out;

  // choose split-K factor to fit workspace (deterministic given ws_size)
  int nc = 16;
  while (nc > 1) {
    size_t fl = (size_t)nc * NQ * 129   // pxt1+pxt2+psum
              + (size_t)nc * NQ * 66    // q1+q2+qs1+qs2
              + (size_t)NQ * 128        // xt1+xt2
              + 3 * (size_t)NS + NQ     // norms
              + 2 * LL * LL             // eld tables
              + 3 * NQ;                 // matchIdx,yid1,yid2 (int)
    if (fl * 4 + 256 <= ws_size) break;
    nc >>= 1;
  }
  const int nc1 = nc, nc2 = nc;

  float* p = (float*)d_ws;
  float* pxt1 = p; p += (size_t)nc1 * NQ * DD;
  float* pxt2 = p; p += (size_t)nc1 * NQ * DD;
  float* psum = p; p += (size_t)nc1 * NQ;
  float* q1   = p; p += (size_t)nc2 * NQ * DY;
  float* q2   = p; p += (size_t)nc2 * NQ * DY;
  float* qs1  = p; p += (size_t)nc2 * NQ;
  float* qs2  = p; p += (size_t)nc2 * NQ;
  float* xt1  = p; p += (size_t)NQ * DD;
  float* xt2  = p; p += (size_t)NQ * DD;
  float* ns   = p; p += NS;
  float* nf1  = p; p += NS;
  float* nf2  = p; p += NS;
  float* nx   = p; p += NQ;
  float* e1   = p; p += LL * LL;
  float* e2   = p; p += LL * LL;
  int* matchIdx = (int*)p; p += NQ;
  int* yid1 = (int*)p; p += NQ;
  int* yid2 = (int*)p;

  const int chunk1 = (((NS + nc1 - 1) / nc1) + 7) & ~7;
  const int chunk2 = (((NS + nc2 - 1) / nc2) + 7) & ~7;

  k_init<<<(NS + NQ + LL * LL + 255) / 256, 256, 0, stream>>>(
      star, f1, f2, x, ld1, ld2, ns, nf1, nf2, nx, e1, e2, matchIdx);
  k_star<<<dim3(NQ / 64, nc1), 256, 0, stream>>>(
      x, star, f1, f2, ns, nx, pxt1, pxt2, psum, matchIdx, chunk1);
  k_mid<<<NQ / 4, 256, 0, stream>>>(
      pxt1, pxt2, psum, matchIdx, f1, f2, W1, b1, W2, b2, u1, u2,
      xt1, xt2, yid1, yid2, nc1);
  k_out<<<dim3(NQ / 64, nc2), 256, 0, stream>>>(
      xt1, f1, slab, nf1, lidx1, yid1, e1, q1, qs1, chunk2);
  k_out<<<dim3(NQ / 64, nc2), 256, 0, stream>>>(
      xt2, f2, slab, nf2, lidx2, yid2, e2, q2, qs2, chunk2);
  k_fin<<<(NQ * DY + 255) / 256, 256, 0, stream>>>(q1, qs1, q2, qs2, out, nc2);
}